// Round 20
// baseline (220.038 us; speedup 1.0000x reference)
//
#include <hip/hip_runtime.h>
#include <hip/hip_bf16.h>

typedef unsigned short u16;
typedef __attribute__((ext_vector_type(8)))  __bf16 bf16x8;
typedef __attribute__((ext_vector_type(8)))  unsigned short u16x8;
typedef __attribute__((ext_vector_type(4)))  unsigned short u16x4;
typedef __attribute__((ext_vector_type(4)))  float f32x4;
typedef __attribute__((ext_vector_type(16))) float f32x16;
typedef __attribute__((ext_vector_type(4)))  unsigned u32x4;

#define MFMA(a, b, c)   __builtin_amdgcn_mfma_f32_16x16x32_bf16((a), (b), (c), 0, 0, 0)
#define MFMA32(a, b, c) __builtin_amdgcn_mfma_f32_32x32x16_bf16((a), (b), (c), 0, 0, 0)

// f32 -> bf16 round-to-nearest-even (bit trick)
__device__ __forceinline__ u16 f2b(float f) {
  union { float f; unsigned u; } x; x.f = f;
  unsigned r = x.u + 0x7fffu + ((x.u >> 16) & 1u);
  return (u16)(r >> 16);
}

// packed f32x2 -> bf16x2 via native casts (compiler emits packed cvt; asm variant was -9%)
__device__ __forceinline__ unsigned pack2(float lo, float hi) {
  const __bf16 a = (__bf16)lo, b = (__bf16)hi;
  return (unsigned)__builtin_bit_cast(u16, a) | ((unsigned)__builtin_bit_cast(u16, b) << 16);
}

// two 8B LDS loads -> one bf16x8 fragment (for 136B-stride rows: 2-way banks, 8B aligned)
__device__ __forceinline__ bf16x8 ld2x64(const u16* p) {
  union { u16x4 h[2]; bf16x8 v; } u;
  u.h[0] = *(const u16x4*)p;
  u.h[1] = *(const u16x4*)(p + 4);
  return u.v;
}

__device__ __forceinline__ void gl_lds16(void* lds, const void* g) {
  __builtin_amdgcn_global_load_lds(
      (const __attribute__((address_space(1))) void*)g,
      (__attribute__((address_space(3))) void*)lds, 16, 0, 0);
}

// ---------------- fused conversions: f32->bf16 copy (x) + all 4 weight transposes ----------
// grid = 8192 (x-convert) + 160*64 (transposes). One launch instead of two.
__global__ __launch_bounds__(256) void cvt_fused_kernel(
    const float* __restrict__ x, u16* __restrict__ xb,
    const float* __restrict__ Wq, const float* __restrict__ Wk,
    const float* __restrict__ Wv, const float* __restrict__ Wo,
    u16* __restrict__ Wqt, u16* __restrict__ Wkt,
    u16* __restrict__ Wvt, u16* __restrict__ Wot) {
  __shared__ u16 t[32][36];
  if (blockIdx.x < 8192) {
    const int i = (blockIdx.x * 256 + threadIdx.x) * 4;
    f32x4 v = *(const f32x4*)(x + i);
    u16x4 o;
    o[0] = f2b(v[0]); o[1] = f2b(v[1]); o[2] = f2b(v[2]); o[3] = f2b(v[3]);
    *(u16x4*)(xb + i) = o;
    return;
  }
  const int bx = blockIdx.x - 8192;
  const int xw = bx >> 6;           // 0..159: weight/column-block selector
  const int k0 = (bx & 63) * 32;
  const float* W; u16* Wt; int N, n0;
  if (xw < 64)      { W = Wq; Wt = Wqt; N = 2048; n0 = xw * 32; }
  else if (xw < 80) { W = Wk; Wt = Wkt; N = 512;  n0 = (xw - 64) * 32; }
  else if (xw < 96) { W = Wv; Wt = Wvt; N = 512;  n0 = (xw - 80) * 32; }
  else              { W = Wo; Wt = Wot; N = 2048; n0 = (xw - 96) * 32; }
  const int r = threadIdx.x >> 3, c4 = (threadIdx.x & 7) * 4;
  f32x4 v = *(const f32x4*)&W[(size_t)(k0 + r) * N + n0 + c4];
  t[c4 + 0][r] = f2b(v[0]);
  t[c4 + 1][r] = f2b(v[1]);
  t[c4 + 2][r] = f2b(v[2]);
  t[c4 + 3][r] = f2b(v[3]);
  __syncthreads();
  u16x4 o;
  o[0] = t[r][c4]; o[1] = t[r][c4 + 1]; o[2] = t[r][c4 + 2]; o[3] = t[r][c4 + 3];
  *(u16x4*)&Wt[(size_t)(n0 + r) * 2048 + k0 + c4] = o;
}

// ---------------- BK=32 GEMM body (R12-proven; oproj control) ----------------
template <bool OUT_BF16>
__device__ __forceinline__ void gemm_body(const u16* __restrict__ A, const u16* __restrict__ Bt,
                                          const float* __restrict__ bias, void* __restrict__ C,
                                          const int N, const int n0, const int m0, const float scale) {
  __shared__ __align__(16) u16 As[128 * 32];
  __shared__ __align__(16) u16 Bs[128 * 32];
  const int tid = threadIdx.x;
  const int lane = tid & 63, wv = tid >> 6;
  const int l15 = lane & 15, lg = lane >> 4;
  const int wm = wv >> 2, wn = wv & 3;     // 2 x 4 wave grid
  const int srow = tid >> 2;               // staging row 0..127
  const int g = tid & 3;
  const int gs = g ^ ((srow >> 1) & 3);    // inverse-swizzled source chunk (rule #21)

  f32x4 acc[4][2] = {};

  for (int k0 = 0; k0 < 2048; k0 += 32) {
    gl_lds16(&As[wv << 9], A  + (((size_t)(m0 + srow)) << 11) + k0 + gs * 8);
    gl_lds16(&Bs[wv << 9], Bt + (((size_t)(n0 + srow)) << 11) + k0 + gs * 8);
    __syncthreads();
    bf16x8 af[4], bfr[2];
#pragma unroll
    for (int t = 0; t < 4; t++) {
      const int ra = wm * 64 + t * 16 + l15;
      af[t] = *(const bf16x8*)&As[ra * 32 + ((lg ^ ((ra >> 1) & 3)) << 3)];
    }
#pragma unroll
    for (int u = 0; u < 2; u++) {
      const int rb = wn * 32 + u * 16 + l15;
      bfr[u] = *(const bf16x8*)&Bs[rb * 32 + ((lg ^ ((rb >> 1) & 3)) << 3)];
    }
#pragma unroll
    for (int mt = 0; mt < 4; mt++)
#pragma unroll
      for (int nt = 0; nt < 2; nt++)
        acc[mt][nt] = MFMA(af[mt], bfr[nt], acc[mt][nt]);
    __syncthreads();
  }

#pragma unroll
  for (int nt = 0; nt < 2; nt++) {
    const int col = n0 + wn * 32 + nt * 16 + l15;
    const float bc = bias[col];
#pragma unroll
    for (int mt = 0; mt < 4; mt++) {
#pragma unroll
      for (int r = 0; r < 4; r++) {
        const int row = m0 + wm * 64 + mt * 16 + lg * 4 + r;
        const float v = (acc[mt][nt][r] + bc) * scale;
        if (OUT_BF16) ((u16*)C)[(size_t)row * N + col] = f2b(v);
        else          ((float*)C)[(size_t)row * N + col] = v;
      }
    }
  }
}

// ---------------- BK=64 GEMM body (qkv experiment: half the barrier count) ----------------
// [128][64]-u16 tiles (32KB LDS total, still 3 blocks/CU at 6 waves/EU). Staging: 2 chunks per
// thread per matrix, 8-slot XOR swizzle (chunk ^= row&7) both-sides (rule #21; same class as
// m201's st_16x32 for 128B rows). Frag reads per ks-half reuse the same af/bfr registers.
__device__ __forceinline__ void gemm_body64(const u16* __restrict__ A, const u16* __restrict__ Bt,
                                            const float* __restrict__ bias, u16* __restrict__ C,
                                            const int N, const int n0, const int m0, const float scale) {
  __shared__ __align__(16) u16 As[128 * 64];
  __shared__ __align__(16) u16 Bs[128 * 64];
  const int tid = threadIdx.x;
  const int lane = tid & 63, wv = tid >> 6;
  const int l15 = lane & 15, lg = lane >> 4;
  const int wm = wv >> 2, wn = wv & 3;     // 2 x 4 wave grid
  const int r0c = tid >> 3, g0 = tid & 7;  // chunk s=0: row, 16B-chunk
  const int r1c = (tid + 512) >> 3;        // chunk s=1 row (g same)
  const int gs0 = g0 ^ (r0c & 7);          // inverse-swizzled source chunks
  const int gs1 = g0 ^ (r1c & 7);

  f32x4 acc[4][2] = {};

  for (int k0 = 0; k0 < 2048; k0 += 64) {
    // stage A,B tiles: 1024 chunks each, 2 per thread; linear LDS dest, pre-swizzled source
    gl_lds16(&As[(wv << 6) * 8],        A  + (((size_t)(m0 + r0c)) << 11) + k0 + gs0 * 8);
    gl_lds16(&As[((wv << 6) + 512) * 8], A + (((size_t)(m0 + r1c)) << 11) + k0 + gs1 * 8);
    gl_lds16(&Bs[(wv << 6) * 8],        Bt + (((size_t)(n0 + r0c)) << 11) + k0 + gs0 * 8);
    gl_lds16(&Bs[((wv << 6) + 512) * 8], Bt + (((size_t)(n0 + r1c)) << 11) + k0 + gs1 * 8);
    __syncthreads();
#pragma unroll
    for (int ks = 0; ks < 2; ks++) {
      bf16x8 af[4], bfr[2];
#pragma unroll
      for (int t = 0; t < 4; t++) {
        const int ra = wm * 64 + t * 16 + l15;
        const int cidx = ks * 4 + lg;
        af[t] = *(const bf16x8*)&As[ra * 64 + ((cidx ^ (ra & 7)) << 3)];
      }
#pragma unroll
      for (int u = 0; u < 2; u++) {
        const int rb = wn * 32 + u * 16 + l15;
        const int cidx = ks * 4 + lg;
        bfr[u] = *(const bf16x8*)&Bs[rb * 64 + ((cidx ^ (rb & 7)) << 3)];
      }
#pragma unroll
      for (int mt = 0; mt < 4; mt++)
#pragma unroll
        for (int nt = 0; nt < 2; nt++)
          acc[mt][nt] = MFMA(af[mt], bfr[nt], acc[mt][nt]);
    }
    __syncthreads();
  }

#pragma unroll
  for (int nt = 0; nt < 2; nt++) {
    const int col = n0 + wn * 32 + nt * 16 + l15;
    const float bc = bias[col];
#pragma unroll
    for (int mt = 0; mt < 4; mt++) {
#pragma unroll
      for (int r = 0; r < 4; r++) {
        const int row = m0 + wm * 64 + mt * 16 + lg * 4 + r;
        C[(size_t)row * N + col] = f2b((acc[mt][nt][r] + bc) * scale);
      }
    }
  }
}

// Fused QKV projection (BK=64 experiment). Q pre-scaled by (1/sqrt(64)) * log2(e).
__global__ __launch_bounds__(512, 6) void qkv_gemm_kernel(
    const u16* __restrict__ xb,
    const u16* __restrict__ Wqt, const u16* __restrict__ Wkt, const u16* __restrict__ Wvt,
    const float* __restrict__ bq, const float* __restrict__ bk, const float* __restrict__ bv,
    u16* __restrict__ Qb, u16* __restrict__ Kb, u16* __restrict__ Vb) {
  const int nb = blockIdx.x;
  const u16* Bt; const float* bias; u16* out; int N, n0; float scale;
  if (nb < 16)      { Bt = Wqt; bias = bq; out = Qb; N = 2048; n0 = nb * 128;        scale = 0.125f * 1.44269504f; }
  else if (nb < 20) { Bt = Wkt; bias = bk; out = Kb; N = 512;  n0 = (nb - 16) * 128; scale = 1.0f; }
  else              { Bt = Wvt; bias = bv; out = Vb; N = 512;  n0 = (nb - 20) * 128; scale = 1.0f; }
  gemm_body64(xb, Bt, bias, out, N, n0, blockIdx.y * 128, scale);
}

// O-projection: BK=32 proven body (in-run control for the BK A/B).
__global__ __launch_bounds__(512, 6) void oproj_kernel(const u16* __restrict__ Ab,
                                                       const u16* __restrict__ Wot,
                                                       const float* __restrict__ bo,
                                                       float* __restrict__ out) {
  gemm_body<false>(Ab, Wot, bo, out, 2048, blockIdx.x * 128, blockIdx.y * 128, 1.0f);
}

// ---------------- causal GQA flash attention (32x32 swapped-operand, fully in-register P) ----
// EXACT R15/R18 kernel (best measured: attn 86.4 us). Parked at its structural plateau:
// R12/R13 block-shape variants, R16/R17 reorderings, R19 waves_per_eu all neutral-or-worse.
__global__ __launch_bounds__(512, 4) void attn_kernel(const u16* __restrict__ Qb,
                                                      const u16* __restrict__ Kb,
                                                      const u16* __restrict__ Vb,
                                                      u16* __restrict__ Ab) {
  const int i = blockIdx.x;
  const int j = i & 255;
  const int kh = j & 7, b = (j >> 3) & 1;
  const int p16 = j >> 4;                       // 0..15
  const int qt = (i < 256) ? (31 - p16) : p16;  // complementary-length pairing

  const int tid = threadIdx.x;
  const int lane = tid & 63, wv = tid >> 6;
  const int hh = wv & 3, qh = wv >> 2;      // head-in-group, q-half
  const int h = kh * 4 + hh;
  const int l31 = lane & 31, hi = lane >> 5;
  const int swz = (l31 & 7) << 3;

  __shared__ __align__(16) u16 Ks[2][64 * 64];   // K[kv][d ^ ((kv&7)<<3)] (gl_lds, rule #21)
  __shared__ __align__(16) u16 Vt[2][64 * 68];   // V^T[d][kv], stride 68 (2-way banks)

  const int skv = tid >> 3;      // kv row staged by this thread (0..63)
  const int sc8 = tid & 7;       // 16B chunk / d0-block
  const int sd0 = sc8 * 8;

  const u16* Kbase = Kb + (size_t)(b * 2048) * 512 + kh * 64;
  const u16* Vbase = Vb + (size_t)(b * 2048) * 512 + kh * 64;

  const int q0 = qt * 64;

  // Q B-frags: col = q = l31, k = d = c*16 + hi*8 + j
  bf16x8 qf[4];
  {
    const u16* qp = Qb + (size_t)(b * 2048 + q0 + qh * 32 + l31) * 2048 + h * 64 + hi * 8;
#pragma unroll
    for (int c = 0; c < 4; c++) qf[c] = *(const bf16x8*)(qp + c * 16);
  }
  f32x16 ot[2] = {};              // O^T acc: row d = dh*32 + (reg&3)+8*(reg>>2)+4*hi, col q
  float mrow = -30000.0f, srow = 0.f;

  int cur = 0;
  {  // prologue: stage tile 0 into buf 0
    gl_lds16(&Ks[0][wv << 9], Kbase + ((size_t)skv << 9) + ((sc8 ^ (skv & 7)) << 3));
    u16x8 vr = *(const u16x8*)(Vbase + ((size_t)skv << 9) + sd0);
#pragma unroll
    for (int j8 = 0; j8 < 8; j8++) {
      const int jj = (j8 + sc8) & 7;      // rotate so concurrent lanes spread banks
      const int d = sd0 + jj;
      Vt[0][d * 68 + skv] = vr[jj];
    }
  }
  for (int it = 0; it <= qt; ++it) {
    __syncthreads();   // buf[cur] fully staged (drains each wave's vmcnt+lgkm, then barrier)
    const bool pre = (it < qt);
    u16x8 vnx;
    if (pre) {  // issue next tile's loads early; V LDS-write deferred past compute
      const size_t roff = (size_t)((it + 1) * 64 + skv) << 9;
      gl_lds16(&Ks[cur ^ 1][wv << 9], Kbase + roff + ((sc8 ^ (skv & 7)) << 3));
      vnx = *(const u16x8*)(Vbase + roff + sd0);
    }
    const u16* Kc = Ks[cur];
    const u16* Vc = Vt[cur];

    // S = K Q : sc2[kvh] rows kv = kvh*32 + (reg&3)+8*(reg>>2)+4*hi, col q = l31
    f32x16 sc2[2] = {};
#pragma unroll
    for (int c = 0; c < 4; c++) {
      const int dblk = (c * 16 + hi * 8) ^ swz;
#pragma unroll
      for (int kvh = 0; kvh < 2; kvh++) {
        bf16x8 kf = *(const bf16x8*)&Kc[(kvh * 32 + l31) * 64 + dblk];
        sc2[kvh] = MFMA32(kf, qf[c], sc2[kvh]);
      }
    }
    if (it == qt) {  // causal mask on diagonal tile
      const int q = qh * 32 + l31;
#pragma unroll
      for (int kvh = 0; kvh < 2; kvh++)
#pragma unroll
        for (int r = 0; r < 16; r++) {
          const int kv = kvh * 32 + (r & 3) + 8 * (r >> 2) + 4 * hi;
          if (kv > q) sc2[kvh][r] = -30000.0f;
        }
    }
    // row max: in-register over this lane's 32 rows + partner lane (other 32)
    float tm = fmaxf(sc2[0][0], sc2[0][1]);
#pragma unroll
    for (int kvh = 0; kvh < 2; kvh++)
#pragma unroll
      for (int r = (kvh ? 0 : 2); r < 16; r++) tm = fmaxf(tm, sc2[kvh][r]);
    tm = fmaxf(tm, __shfl_xor(tm, 32));
    // defer-max (T13): rescale only if max grew by > 8 (log2 units)
    if (__any(tm > mrow + 8.0f)) {
      const float mnew = fmaxf(mrow, tm);
      const float scl = __builtin_amdgcn_exp2f(mrow - mnew);
      mrow = mnew;
      srow *= scl;
#pragma unroll
      for (int dh = 0; dh < 2; dh++)
#pragma unroll
        for (int r = 0; r < 16; r++) ot[dh][r] *= scl;
    }
    // P = exp2(S - m), packed in-register; PV per kvh-half (only 8 pk words live at a time)
    float ps = 0.f;
#pragma unroll
    for (int kvh = 0; kvh < 2; kvh++) {
      unsigned pk[8];
#pragma unroll
      for (int j8 = 0; j8 < 8; j8++) {
        const float p0 = __builtin_amdgcn_exp2f(sc2[kvh][2 * j8] - mrow);
        const float p1 = __builtin_amdgcn_exp2f(sc2[kvh][2 * j8 + 1] - mrow);
        ps += p0 + p1;
        pk[j8] = pack2(p0, p1);     // kv pair base 8*(j8>>1)+2*(j8&1)+4*hi (+32*kvh)
      }
      // O^T += V^T P for chunks t = 2*kvh + tt
#pragma unroll
      for (int tt = 0; tt < 2; tt++) {
        const int t = kvh * 2 + tt;
        const unsigned a0 = pk[4 * tt + 0], a1 = pk[4 * tt + 1];
        const unsigned b0 = pk[4 * tt + 2], b1 = pk[4 * tt + 3];
        // send what the PARTNER needs; receive what WE need (partner's 4*tt + 2*hi + q)
        const unsigned s0 = hi ? a0 : b0, s1 = hi ? a1 : b1;
        const unsigned r0 = (unsigned)__shfl_xor((int)s0, 32);
        const unsigned r1 = (unsigned)__shfl_xor((int)s1, 32);
        u32x4 pw;
        pw[0] = hi ? r0 : a0;   // kv 16t+8hi+0,1
        pw[1] = hi ? r1 : a1;   // kv 16t+8hi+2,3
        pw[2] = hi ? b0 : r0;   // kv 16t+8hi+4,5
        pw[3] = hi ? b1 : r1;   // kv 16t+8hi+6,7
        const bf16x8 pf = __builtin_bit_cast(bf16x8, pw);
#pragma unroll
        for (int dh = 0; dh < 2; dh++) {
          bf16x8 vf = ld2x64(&Vc[(dh * 32 + l31) * 68 + t * 16 + hi * 8]);
          ot[dh] = MFMA32(vf, pf, ot[dh]);
        }
      }
    }
    ps += __shfl_xor(ps, 32);
    srow += ps;
    if (pre) {  // deferred V write into next buffer
#pragma unroll
      for (int j8 = 0; j8 < 8; j8++) {
        const int jj = (j8 + sc8) & 7;
        const int d = sd0 + jj;
        Vt[cur ^ 1][d * 68 + skv] = vnx[jj];
      }
    }
    cur ^= 1;
  }
  // epilogue: transpose O^T -> O through LDS (K/V buffers are dead), coalesced store
  __syncthreads();                     // all waves done reading K/V
  u16* Sx = (wv < 4) ? &Ks[0][0] + wv * 2048 : &Vt[0][0] + (wv - 4) * 2048;  // 4KB/wave scratch
  const float inv = 1.0f / srow;
#pragma unroll
  for (int dh = 0; dh < 2; dh++)
#pragma unroll
    for (int jr = 0; jr < 8; jr++) {   // regs (2jr, 2jr+1) -> adjacent d
      const unsigned w = pack2(ot[dh][2 * jr] * inv, ot[dh][2 * jr + 1] * inv);
      const int d = dh * 32 + 8 * (jr >> 1) + (jr & 1) * 2 + 4 * hi;
      *(unsigned*)&Sx[l31 * 64 + (d ^ swz)] = w;
    }
  __syncthreads();   // make scratch writes visible before readback
#pragma unroll
  for (int rep = 0; rep < 4; rep++) {
    const int chunk = rep * 64 + lane;
    const int qr = chunk >> 3, cc = chunk & 7;
    u16x8 val = *(const u16x8*)&Sx[qr * 64 + ((cc * 8) ^ ((qr & 7) << 3))];
    *(u16x8*)&Ab[(size_t)(b * 2048 + q0 + qh * 32 + qr) * 2048 + h * 64 + cc * 8] = val;
  }
}

extern "C" void kernel_launch(void* const* d_in, const int* in_sizes, int n_in,
                              void* d_out, int out_size, void* d_ws, size_t ws_size,
                              hipStream_t stream) {
  const float* x  = (const float*)d_in[0];
  const float* Wq = (const float*)d_in[1];
  const float* bq = (const float*)d_in[2];
  const float* Wk = (const float*)d_in[3];
  const float* bk = (const float*)d_in[4];
  const float* Wv = (const float*)d_in[5];
  const float* bv = (const float*)d_in[6];
  const float* Wo = (const float*)d_in[7];
  const float* bo = (const float*)d_in[8];

  char* ws = (char*)d_ws;
  u16* xb  = (u16*)(ws + 0);          // 4096*2048 bf16 = 16 MiB
  u16* Ab  = (u16*)(ws + 0);          // aliases xb (xb dead after QKV gemm)
  u16* Qb  = (u16*)(ws + 16777216);   // 4096*2048
  u16* Kb  = (u16*)(ws + 33554432);   // 4096*512
  u16* Vb  = (u16*)(ws + 37748736);   // 4096*512
  u16* Wqt = (u16*)(ws + 41943040);   // 2048*2048
  u16* Wkt = (u16*)(ws + 50331648);   // 512*2048
  u16* Wvt = (u16*)(ws + 52428800);   // 512*2048
  u16* Wot = (u16*)(ws + 54525952);   // 2048*2048

  cvt_fused_kernel<<<dim3(8192 + 160 * 64), 256, 0, stream>>>(
      x, xb, Wq, Wk, Wv, Wo, Wqt, Wkt, Wvt, Wot);

  qkv_gemm_kernel<<<dim3(24, 32), 512, 0, stream>>>(xb, Wqt, Wkt, Wvt, bq, bk, bv, Qb, Kb, Vb);
  attn_kernel<<<dim3(512), 512, 0, stream>>>(Qb, Kb, Vb, Ab);
  oproj_kernel<<<dim3(16, 32), 512, 0, stream>>>(Ab, Wot, bo, (float*)d_out);
}

// Round 21
// 211.378 us; speedup vs baseline: 1.0410x; 1.0410x over previous
//
#include <hip/hip_runtime.h>
#include <hip/hip_bf16.h>

typedef unsigned short u16;
typedef __attribute__((ext_vector_type(8)))  __bf16 bf16x8;
typedef __attribute__((ext_vector_type(8)))  unsigned short u16x8;
typedef __attribute__((ext_vector_type(4)))  unsigned short u16x4;
typedef __attribute__((ext_vector_type(4)))  float f32x4;
typedef __attribute__((ext_vector_type(16))) float f32x16;
typedef __attribute__((ext_vector_type(4)))  unsigned u32x4;

#define MFMA(a, b, c)   __builtin_amdgcn_mfma_f32_16x16x32_bf16((a), (b), (c), 0, 0, 0)
#define MFMA32(a, b, c) __builtin_amdgcn_mfma_f32_32x32x16_bf16((a), (b), (c), 0, 0, 0)

// f32 -> bf16 round-to-nearest-even (bit trick)
__device__ __forceinline__ u16 f2b(float f) {
  union { float f; unsigned u; } x; x.f = f;
  unsigned r = x.u + 0x7fffu + ((x.u >> 16) & 1u);
  return (u16)(r >> 16);
}

// packed f32x2 -> bf16x2 via native casts (compiler emits packed cvt; asm variant was -9%)
__device__ __forceinline__ unsigned pack2(float lo, float hi) {
  const __bf16 a = (__bf16)lo, b = (__bf16)hi;
  return (unsigned)__builtin_bit_cast(u16, a) | ((unsigned)__builtin_bit_cast(u16, b) << 16);
}

// two 8B LDS loads -> one bf16x8 fragment (for 136B-stride rows: 2-way banks, 8B aligned)
__device__ __forceinline__ bf16x8 ld2x64(const u16* p) {
  union { u16x4 h[2]; bf16x8 v; } u;
  u.h[0] = *(const u16x4*)p;
  u.h[1] = *(const u16x4*)(p + 4);
  return u.v;
}

__device__ __forceinline__ void gl_lds16(void* lds, const void* g) {
  __builtin_amdgcn_global_load_lds(
      (const __attribute__((address_space(1))) void*)g,
      (__attribute__((address_space(3))) void*)lds, 16, 0, 0);
}

// ---------------- fused conversions: f32->bf16 copy (x) + all 4 weight transposes ----------
// grid = 8192 (x-convert) + 160*64 (transposes). One launch instead of two.
__global__ __launch_bounds__(256) void cvt_fused_kernel(
    const float* __restrict__ x, u16* __restrict__ xb,
    const float* __restrict__ Wq, const float* __restrict__ Wk,
    const float* __restrict__ Wv, const float* __restrict__ Wo,
    u16* __restrict__ Wqt, u16* __restrict__ Wkt,
    u16* __restrict__ Wvt, u16* __restrict__ Wot) {
  __shared__ u16 t[32][36];
  if (blockIdx.x < 8192) {
    const int i = (blockIdx.x * 256 + threadIdx.x) * 4;
    f32x4 v = *(const f32x4*)(x + i);
    u16x4 o;
    o[0] = f2b(v[0]); o[1] = f2b(v[1]); o[2] = f2b(v[2]); o[3] = f2b(v[3]);
    *(u16x4*)(xb + i) = o;
    return;
  }
  const int bx = blockIdx.x - 8192;
  const int xw = bx >> 6;           // 0..159: weight/column-block selector
  const int k0 = (bx & 63) * 32;
  const float* W; u16* Wt; int N, n0;
  if (xw < 64)      { W = Wq; Wt = Wqt; N = 2048; n0 = xw * 32; }
  else if (xw < 80) { W = Wk; Wt = Wkt; N = 512;  n0 = (xw - 64) * 32; }
  else if (xw < 96) { W = Wv; Wt = Wvt; N = 512;  n0 = (xw - 80) * 32; }
  else              { W = Wo; Wt = Wot; N = 2048; n0 = (xw - 96) * 32; }
  const int r = threadIdx.x >> 3, c4 = (threadIdx.x & 7) * 4;
  f32x4 v = *(const f32x4*)&W[(size_t)(k0 + r) * N + n0 + c4];
  t[c4 + 0][r] = f2b(v[0]);
  t[c4 + 1][r] = f2b(v[1]);
  t[c4 + 2][r] = f2b(v[2]);
  t[c4 + 3][r] = f2b(v[3]);
  __syncthreads();
  u16x4 o;
  o[0] = t[r][c4]; o[1] = t[r][c4 + 1]; o[2] = t[r][c4 + 2]; o[3] = t[r][c4 + 3];
  *(u16x4*)&Wt[(size_t)(n0 + r) * 2048 + k0 + c4] = o;
}

// ---------------- BK=32 GEMM body (R12-proven; the 2-barrier template's converged point) ----
// BK axis closed: R8's 2-phase dbuf and R20's BK=64 both regressed — at 3 blocks/CU the
// cross-block TLP already hides the per-step vmcnt drain; bigger K-tiles only lengthen the
// single-block critical path. ~858 TF ≈ the m97-family structure ceiling.
template <bool OUT_BF16>
__device__ __forceinline__ void gemm_body(const u16* __restrict__ A, const u16* __restrict__ Bt,
                                          const float* __restrict__ bias, void* __restrict__ C,
                                          const int N, const int n0, const int m0, const float scale) {
  __shared__ __align__(16) u16 As[128 * 32];
  __shared__ __align__(16) u16 Bs[128 * 32];
  const int tid = threadIdx.x;
  const int lane = tid & 63, wv = tid >> 6;
  const int l15 = lane & 15, lg = lane >> 4;
  const int wm = wv >> 2, wn = wv & 3;     // 2 x 4 wave grid
  const int srow = tid >> 2;               // staging row 0..127
  const int g = tid & 3;
  const int gs = g ^ ((srow >> 1) & 3);    // inverse-swizzled source chunk (rule #21)

  f32x4 acc[4][2] = {};

  for (int k0 = 0; k0 < 2048; k0 += 32) {
    gl_lds16(&As[wv << 9], A  + (((size_t)(m0 + srow)) << 11) + k0 + gs * 8);
    gl_lds16(&Bs[wv << 9], Bt + (((size_t)(n0 + srow)) << 11) + k0 + gs * 8);
    __syncthreads();
    bf16x8 af[4], bfr[2];
#pragma unroll
    for (int t = 0; t < 4; t++) {
      const int ra = wm * 64 + t * 16 + l15;
      af[t] = *(const bf16x8*)&As[ra * 32 + ((lg ^ ((ra >> 1) & 3)) << 3)];
    }
#pragma unroll
    for (int u = 0; u < 2; u++) {
      const int rb = wn * 32 + u * 16 + l15;
      bfr[u] = *(const bf16x8*)&Bs[rb * 32 + ((lg ^ ((rb >> 1) & 3)) << 3)];
    }
#pragma unroll
    for (int mt = 0; mt < 4; mt++)
#pragma unroll
      for (int nt = 0; nt < 2; nt++)
        acc[mt][nt] = MFMA(af[mt], bfr[nt], acc[mt][nt]);
    __syncthreads();
  }

#pragma unroll
  for (int nt = 0; nt < 2; nt++) {
    const int col = n0 + wn * 32 + nt * 16 + l15;
    const float bc = bias[col];
#pragma unroll
    for (int mt = 0; mt < 4; mt++) {
#pragma unroll
      for (int r = 0; r < 4; r++) {
        const int row = m0 + wm * 64 + mt * 16 + lg * 4 + r;
        const float v = (acc[mt][nt][r] + bc) * scale;
        if (OUT_BF16) ((u16*)C)[(size_t)row * N + col] = f2b(v);
        else          ((float*)C)[(size_t)row * N + col] = v;
      }
    }
  }
}

// Fused QKV projection. Q is pre-scaled by (1/sqrt(64)) * log2(e) so attention uses exp2.
__global__ __launch_bounds__(512, 6) void qkv_gemm_kernel(
    const u16* __restrict__ xb,
    const u16* __restrict__ Wqt, const u16* __restrict__ Wkt, const u16* __restrict__ Wvt,
    const float* __restrict__ bq, const float* __restrict__ bk, const float* __restrict__ bv,
    u16* __restrict__ Qb, u16* __restrict__ Kb, u16* __restrict__ Vb) {
  const int nb = blockIdx.x;
  const u16* Bt; const float* bias; u16* out; int N, n0; float scale;
  if (nb < 16)      { Bt = Wqt; bias = bq; out = Qb; N = 2048; n0 = nb * 128;        scale = 0.125f * 1.44269504f; }
  else if (nb < 20) { Bt = Wkt; bias = bk; out = Kb; N = 512;  n0 = (nb - 16) * 128; scale = 1.0f; }
  else              { Bt = Wvt; bias = bv; out = Vb; N = 512;  n0 = (nb - 20) * 128; scale = 1.0f; }
  gemm_body<true>(xb, Bt, bias, out, N, n0, blockIdx.y * 128, scale);
}

__global__ __launch_bounds__(512, 6) void oproj_kernel(const u16* __restrict__ Ab,
                                                       const u16* __restrict__ Wot,
                                                       const float* __restrict__ bo,
                                                       float* __restrict__ out) {
  gemm_body<false>(Ab, Wot, bo, out, 2048, blockIdx.x * 128, blockIdx.y * 128, 1.0f);
}

// ---------------- causal GQA flash attention (32x32 swapped-operand, fully in-register P) ----
// EXACT R15/R18 kernel (best measured: attn 86.4 us). Parked at its structural plateau.
__global__ __launch_bounds__(512, 4) void attn_kernel(const u16* __restrict__ Qb,
                                                      const u16* __restrict__ Kb,
                                                      const u16* __restrict__ Vb,
                                                      u16* __restrict__ Ab) {
  const int i = blockIdx.x;
  const int j = i & 255;
  const int kh = j & 7, b = (j >> 3) & 1;
  const int p16 = j >> 4;                       // 0..15
  const int qt = (i < 256) ? (31 - p16) : p16;  // complementary-length pairing

  const int tid = threadIdx.x;
  const int lane = tid & 63, wv = tid >> 6;
  const int hh = wv & 3, qh = wv >> 2;      // head-in-group, q-half
  const int h = kh * 4 + hh;
  const int l31 = lane & 31, hi = lane >> 5;
  const int swz = (l31 & 7) << 3;

  __shared__ __align__(16) u16 Ks[2][64 * 64];   // K[kv][d ^ ((kv&7)<<3)] (gl_lds, rule #21)
  __shared__ __align__(16) u16 Vt[2][64 * 68];   // V^T[d][kv], stride 68 (2-way banks)

  const int skv = tid >> 3;      // kv row staged by this thread (0..63)
  const int sc8 = tid & 7;       // 16B chunk / d0-block
  const int sd0 = sc8 * 8;

  const u16* Kbase = Kb + (size_t)(b * 2048) * 512 + kh * 64;
  const u16* Vbase = Vb + (size_t)(b * 2048) * 512 + kh * 64;

  const int q0 = qt * 64;

  // Q B-frags: col = q = l31, k = d = c*16 + hi*8 + j
  bf16x8 qf[4];
  {
    const u16* qp = Qb + (size_t)(b * 2048 + q0 + qh * 32 + l31) * 2048 + h * 64 + hi * 8;
#pragma unroll
    for (int c = 0; c < 4; c++) qf[c] = *(const bf16x8*)(qp + c * 16);
  }
  f32x16 ot[2] = {};              // O^T acc: row d = dh*32 + (reg&3)+8*(reg>>2)+4*hi, col q
  float mrow = -30000.0f, srow = 0.f;

  int cur = 0;
  {  // prologue: stage tile 0 into buf 0
    gl_lds16(&Ks[0][wv << 9], Kbase + ((size_t)skv << 9) + ((sc8 ^ (skv & 7)) << 3));
    u16x8 vr = *(const u16x8*)(Vbase + ((size_t)skv << 9) + sd0);
#pragma unroll
    for (int j8 = 0; j8 < 8; j8++) {
      const int jj = (j8 + sc8) & 7;      // rotate so concurrent lanes spread banks
      const int d = sd0 + jj;
      Vt[0][d * 68 + skv] = vr[jj];
    }
  }
  for (int it = 0; it <= qt; ++it) {
    __syncthreads();   // buf[cur] fully staged (drains each wave's vmcnt+lgkm, then barrier)
    const bool pre = (it < qt);
    u16x8 vnx;
    if (pre) {  // issue next tile's loads early; V LDS-write deferred past compute
      const size_t roff = (size_t)((it + 1) * 64 + skv) << 9;
      gl_lds16(&Ks[cur ^ 1][wv << 9], Kbase + roff + ((sc8 ^ (skv & 7)) << 3));
      vnx = *(const u16x8*)(Vbase + roff + sd0);
    }
    const u16* Kc = Ks[cur];
    const u16* Vc = Vt[cur];

    // S = K Q : sc2[kvh] rows kv = kvh*32 + (reg&3)+8*(reg>>2)+4*hi, col q = l31
    f32x16 sc2[2] = {};
#pragma unroll
    for (int c = 0; c < 4; c++) {
      const int dblk = (c * 16 + hi * 8) ^ swz;
#pragma unroll
      for (int kvh = 0; kvh < 2; kvh++) {
        bf16x8 kf = *(const bf16x8*)&Kc[(kvh * 32 + l31) * 64 + dblk];
        sc2[kvh] = MFMA32(kf, qf[c], sc2[kvh]);
      }
    }
    if (it == qt) {  // causal mask on diagonal tile
      const int q = qh * 32 + l31;
#pragma unroll
      for (int kvh = 0; kvh < 2; kvh++)
#pragma unroll
        for (int r = 0; r < 16; r++) {
          const int kv = kvh * 32 + (r & 3) + 8 * (r >> 2) + 4 * hi;
          if (kv > q) sc2[kvh][r] = -30000.0f;
        }
    }
    // row max: in-register over this lane's 32 rows + partner lane (other 32)
    float tm = fmaxf(sc2[0][0], sc2[0][1]);
#pragma unroll
    for (int kvh = 0; kvh < 2; kvh++)
#pragma unroll
      for (int r = (kvh ? 0 : 2); r < 16; r++) tm = fmaxf(tm, sc2[kvh][r]);
    tm = fmaxf(tm, __shfl_xor(tm, 32));
    // defer-max (T13): rescale only if max grew by > 8 (log2 units)
    if (__any(tm > mrow + 8.0f)) {
      const float mnew = fmaxf(mrow, tm);
      const float scl = __builtin_amdgcn_exp2f(mrow - mnew);
      mrow = mnew;
      srow *= scl;
#pragma unroll
      for (int dh = 0; dh < 2; dh++)
#pragma unroll
        for (int r = 0; r < 16; r++) ot[dh][r] *= scl;
    }
    // P = exp2(S - m), packed in-register; PV per kvh-half (only 8 pk words live at a time)
    float ps = 0.f;
#pragma unroll
    for (int kvh = 0; kvh < 2; kvh++) {
      unsigned pk[8];
#pragma unroll
      for (int j8 = 0; j8 < 8; j8++) {
        const float p0 = __builtin_amdgcn_exp2f(sc2[kvh][2 * j8] - mrow);
        const float p1 = __builtin_amdgcn_exp2f(sc2[kvh][2 * j8 + 1] - mrow);
        ps += p0 + p1;
        pk[j8] = pack2(p0, p1);     // kv pair base 8*(j8>>1)+2*(j8&1)+4*hi (+32*kvh)
      }
      // O^T += V^T P for chunks t = 2*kvh + tt
#pragma unroll
      for (int tt = 0; tt < 2; tt++) {
        const int t = kvh * 2 + tt;
        const unsigned a0 = pk[4 * tt + 0], a1 = pk[4 * tt + 1];
        const unsigned b0 = pk[4 * tt + 2], b1 = pk[4 * tt + 3];
        // send what the PARTNER needs; receive what WE need (partner's 4*tt + 2*hi + q)
        const unsigned s0 = hi ? a0 : b0, s1 = hi ? a1 : b1;
        const unsigned r0 = (unsigned)__shfl_xor((int)s0, 32);
        const unsigned r1 = (unsigned)__shfl_xor((int)s1, 32);
        u32x4 pw;
        pw[0] = hi ? r0 : a0;   // kv 16t+8hi+0,1
        pw[1] = hi ? r1 : a1;   // kv 16t+8hi+2,3
        pw[2] = hi ? b0 : r0;   // kv 16t+8hi+4,5
        pw[3] = hi ? b1 : r1;   // kv 16t+8hi+6,7
        const bf16x8 pf = __builtin_bit_cast(bf16x8, pw);
#pragma unroll
        for (int dh = 0; dh < 2; dh++) {
          bf16x8 vf = ld2x64(&Vc[(dh * 32 + l31) * 68 + t * 16 + hi * 8]);
          ot[dh] = MFMA32(vf, pf, ot[dh]);
        }
      }
    }
    ps += __shfl_xor(ps, 32);
    srow += ps;
    if (pre) {  // deferred V write into next buffer
#pragma unroll
      for (int j8 = 0; j8 < 8; j8++) {
        const int jj = (j8 + sc8) & 7;
        const int d = sd0 + jj;
        Vt[cur ^ 1][d * 68 + skv] = vnx[jj];
      }
    }
    cur ^= 1;
  }
  // epilogue: transpose O^T -> O through LDS (K/V buffers are dead), coalesced store
  __syncthreads();                     // all waves done reading K/V
  u16* Sx = (wv < 4) ? &Ks[0][0] + wv * 2048 : &Vt[0][0] + (wv - 4) * 2048;  // 4KB/wave scratch
  const float inv = 1.0f / srow;
#pragma unroll
  for (int dh = 0; dh < 2; dh++)
#pragma unroll
    for (int jr = 0; jr < 8; jr++) {   // regs (2jr, 2jr+1) -> adjacent d
      const unsigned w = pack2(ot[dh][2 * jr] * inv, ot[dh][2 * jr + 1] * inv);
      const int d = dh * 32 + 8 * (jr >> 1) + (jr & 1) * 2 + 4 * hi;
      *(unsigned*)&Sx[l31 * 64 + (d ^ swz)] = w;
    }
  __syncthreads();   // make scratch writes visible before readback
#pragma unroll
  for (int rep = 0; rep < 4; rep++) {
    const int chunk = rep * 64 + lane;
    const int qr = chunk >> 3, cc = chunk & 7;
    u16x8 val = *(const u16x8*)&Sx[qr * 64 + ((cc * 8) ^ ((qr & 7) << 3))];
    *(u16x8*)&Ab[(size_t)(b * 2048 + q0 + qh * 32 + qr) * 2048 + h * 64 + cc * 8] = val;
  }
}

extern "C" void kernel_launch(void* const* d_in, const int* in_sizes, int n_in,
                              void* d_out, int out_size, void* d_ws, size_t ws_size,
                              hipStream_t stream) {
  const float* x  = (const float*)d_in[0];
  const float* Wq = (const float*)d_in[1];
  const float* bq = (const float*)d_in[2];
  const float* Wk = (const float*)d_in[3];
  const float* bk = (const float*)d_in[4];
  const float* Wv = (const float*)d_in[5];
  const float* bv = (const float*)d_in[6];
  const float* Wo = (const float*)d_in[7];
  const float* bo = (const float*)d_in[8];

  char* ws = (char*)d_ws;
  u16* xb  = (u16*)(ws + 0);          // 4096*2048 bf16 = 16 MiB
  u16* Ab  = (u16*)(ws + 0);          // aliases xb (xb dead after QKV gemm)
  u16* Qb  = (u16*)(ws + 16777216);   // 4096*2048
  u16* Kb  = (u16*)(ws + 33554432);   // 4096*512
  u16* Vb  = (u16*)(ws + 37748736);   // 4096*512
  u16* Wqt = (u16*)(ws + 41943040);   // 2048*2048
  u16* Wkt = (u16*)(ws + 50331648);   // 512*2048
  u16* Wvt = (u16*)(ws + 52428800);   // 512*2048
  u16* Wot = (u16*)(ws + 54525952);   // 2048*2048

  cvt_fused_kernel<<<dim3(8192 + 160 * 64), 256, 0, stream>>>(
      x, xb, Wq, Wk, Wv, Wo, Wqt, Wkt, Wvt, Wot);

  qkv_gemm_kernel<<<dim3(24, 32), 512, 0, stream>>>(xb, Wqt, Wkt, Wvt, bq, bk, bv, Qb, Kb, Vb);
  attn_kernel<<<dim3(512), 512, 0, stream>>>(Qb, Kb, Vb, Ab);
  oproj_kernel<<<dim3(16, 32), 512, 0, stream>>>(Ab, Wot, bo, (float*)d_out);
}

// Round 22
// 208.652 us; speedup vs baseline: 1.0546x; 1.0131x over previous
//
#include <hip/hip_runtime.h>
#include <hip/hip_bf16.h>

typedef unsigned short u16;
typedef __attribute__((ext_vector_type(8)))  __bf16 bf16x8;
typedef __attribute__((ext_vector_type(8)))  unsigned short u16x8;
typedef __attribute__((ext_vector_type(4)))  unsigned short u16x4;
typedef __attribute__((ext_vector_type(4)))  float f32x4;
typedef __attribute__((ext_vector_type(16))) float f32x16;
typedef __attribute__((ext_vector_type(4)))  unsigned u32x4;

#define MFMA(a, b, c)   __builtin_amdgcn_mfma_f32_16x16x32_bf16((a), (b), (c), 0, 0, 0)
#define MFMA32(a, b, c) __builtin_amdgcn_mfma_f32_32x32x16_bf16((a), (b), (c), 0, 0, 0)

// f32 -> bf16 round-to-nearest-even (bit trick)
__device__ __forceinline__ u16 f2b(float f) {
  union { float f; unsigned u; } x; x.f = f;
  unsigned r = x.u + 0x7fffu + ((x.u >> 16) & 1u);
  return (u16)(r >> 16);
}

__device__ __forceinline__ float b2f(u16 v) {
  return __builtin_bit_cast(float, ((unsigned)v) << 16);
}

// packed f32x2 -> bf16x2 via native casts (compiler emits packed cvt; asm variant was -9%)
__device__ __forceinline__ unsigned pack2(float lo, float hi) {
  const __bf16 a = (__bf16)lo, b = (__bf16)hi;
  return (unsigned)__builtin_bit_cast(u16, a) | ((unsigned)__builtin_bit_cast(u16, b) << 16);
}

// two 8B LDS loads -> one bf16x8 fragment (for 136B-stride rows: 2-way banks, 8B aligned)
__device__ __forceinline__ bf16x8 ld2x64(const u16* p) {
  union { u16x4 h[2]; bf16x8 v; } u;
  u.h[0] = *(const u16x4*)p;
  u.h[1] = *(const u16x4*)(p + 4);
  return u.v;
}

__device__ __forceinline__ void gl_lds16(void* lds, const void* g) {
  __builtin_amdgcn_global_load_lds(
      (const __attribute__((address_space(1))) void*)g,
      (__attribute__((address_space(3))) void*)lds, 16, 0, 0);
}

// ---------------- fused conversions: f32->bf16 copy (x) + all 4 weight transposes ----------
__global__ __launch_bounds__(256) void cvt_fused_kernel(
    const float* __restrict__ x, u16* __restrict__ xb,
    const float* __restrict__ Wq, const float* __restrict__ Wk,
    const float* __restrict__ Wv, const float* __restrict__ Wo,
    u16* __restrict__ Wqt, u16* __restrict__ Wkt,
    u16* __restrict__ Wvt, u16* __restrict__ Wot) {
  __shared__ u16 t[32][36];
  if (blockIdx.x < 8192) {
    const int i = (blockIdx.x * 256 + threadIdx.x) * 4;
    f32x4 v = *(const f32x4*)(x + i);
    u16x4 o;
    o[0] = f2b(v[0]); o[1] = f2b(v[1]); o[2] = f2b(v[2]); o[3] = f2b(v[3]);
    *(u16x4*)(xb + i) = o;
    return;
  }
  const int bx = blockIdx.x - 8192;
  const int xw = bx >> 6;
  const int k0 = (bx & 63) * 32;
  const float* W; u16* Wt; int N, n0;
  if (xw < 64)      { W = Wq; Wt = Wqt; N = 2048; n0 = xw * 32; }
  else if (xw < 80) { W = Wk; Wt = Wkt; N = 512;  n0 = (xw - 64) * 32; }
  else if (xw < 96) { W = Wv; Wt = Wvt; N = 512;  n0 = (xw - 80) * 32; }
  else              { W = Wo; Wt = Wot; N = 2048; n0 = (xw - 96) * 32; }
  const int r = threadIdx.x >> 3, c4 = (threadIdx.x & 7) * 4;
  f32x4 v = *(const f32x4*)&W[(size_t)(k0 + r) * N + n0 + c4];
  t[c4 + 0][r] = f2b(v[0]);
  t[c4 + 1][r] = f2b(v[1]);
  t[c4 + 2][r] = f2b(v[2]);
  t[c4 + 3][r] = f2b(v[3]);
  __syncthreads();
  u16x4 o;
  o[0] = t[r][c4]; o[1] = t[r][c4 + 1]; o[2] = t[r][c4 + 2]; o[3] = t[r][c4 + 3];
  *(u16x4*)&Wt[(size_t)(n0 + r) * 2048 + k0 + c4] = o;
}

// ---------------- BK=32 GEMM body (converged 2-barrier template) ----------------
template <bool OUT_BF16>
__device__ __forceinline__ void gemm_body(const u16* __restrict__ A, const u16* __restrict__ Bt,
                                          const float* __restrict__ bias, void* __restrict__ C,
                                          const int N, const int n0, const int m0, const float scale) {
  __shared__ __align__(16) u16 As[128 * 32];
  __shared__ __align__(16) u16 Bs[128 * 32];
  const int tid = threadIdx.x;
  const int lane = tid & 63, wv = tid >> 6;
  const int l15 = lane & 15, lg = lane >> 4;
  const int wm = wv >> 2, wn = wv & 3;
  const int srow = tid >> 2;
  const int g = tid & 3;
  const int gs = g ^ ((srow >> 1) & 3);

  f32x4 acc[4][2] = {};

  for (int k0 = 0; k0 < 2048; k0 += 32) {
    gl_lds16(&As[wv << 9], A  + (((size_t)(m0 + srow)) << 11) + k0 + gs * 8);
    gl_lds16(&Bs[wv << 9], Bt + (((size_t)(n0 + srow)) << 11) + k0 + gs * 8);
    __syncthreads();
    bf16x8 af[4], bfr[2];
#pragma unroll
    for (int t = 0; t < 4; t++) {
      const int ra = wm * 64 + t * 16 + l15;
      af[t] = *(const bf16x8*)&As[ra * 32 + ((lg ^ ((ra >> 1) & 3)) << 3)];
    }
#pragma unroll
    for (int u = 0; u < 2; u++) {
      const int rb = wn * 32 + u * 16 + l15;
      bfr[u] = *(const bf16x8*)&Bs[rb * 32 + ((lg ^ ((rb >> 1) & 3)) << 3)];
    }
#pragma unroll
    for (int mt = 0; mt < 4; mt++)
#pragma unroll
      for (int nt = 0; nt < 2; nt++)
        acc[mt][nt] = MFMA(af[mt], bfr[nt], acc[mt][nt]);
    __syncthreads();
  }

#pragma unroll
  for (int nt = 0; nt < 2; nt++) {
    const int col = n0 + wn * 32 + nt * 16 + l15;
    const float bc = bias[col];
#pragma unroll
    for (int mt = 0; mt < 4; mt++) {
#pragma unroll
      for (int r = 0; r < 4; r++) {
        const int row = m0 + wm * 64 + mt * 16 + lg * 4 + r;
        const float v = (acc[mt][nt][r] + bc) * scale;
        if (OUT_BF16) ((u16*)C)[(size_t)row * N + col] = f2b(v);
        else          ((float*)C)[(size_t)row * N + col] = v;
      }
    }
  }
}

__global__ __launch_bounds__(512, 6) void qkv_gemm_kernel(
    const u16* __restrict__ xb,
    const u16* __restrict__ Wqt, const u16* __restrict__ Wkt, const u16* __restrict__ Wvt,
    const float* __restrict__ bq, const float* __restrict__ bk, const float* __restrict__ bv,
    u16* __restrict__ Qb, u16* __restrict__ Kb, u16* __restrict__ Vb) {
  const int nb = blockIdx.x;
  const u16* Bt; const float* bias; u16* out; int N, n0; float scale;
  if (nb < 16)      { Bt = Wqt; bias = bq; out = Qb; N = 2048; n0 = nb * 128;        scale = 0.125f * 1.44269504f; }
  else if (nb < 20) { Bt = Wkt; bias = bk; out = Kb; N = 512;  n0 = (nb - 16) * 128; scale = 1.0f; }
  else              { Bt = Wvt; bias = bv; out = Vb; N = 512;  n0 = (nb - 20) * 128; scale = 1.0f; }
  gemm_body<true>(xb, Bt, bias, out, N, n0, blockIdx.y * 128, scale);
}

__global__ __launch_bounds__(512, 6) void oproj_kernel(const u16* __restrict__ Ab,
                                                       const u16* __restrict__ Wot,
                                                       const float* __restrict__ bo,
                                                       float* __restrict__ out) {
  gemm_body<false>(Ab, Wot, bo, out, 2048, blockIdx.x * 128, blockIdx.y * 128, 1.0f);
}

// ---------------- causal GQA flash attention: bounded split-KV for load balance ------------
// 688 blocks = 16 (b,kh) x 43 chunks. Tiles qt<=20 are solo chunks; tiles qt=21..31 split into
// two KV-tile halves. Chunks ordered longest-first (kOrder) so HW backfill smooths the tail:
// old complementary pairing had worst-CU wall = 32 iters at half residency; now max chunk = 21.
// Split chunks write normalized bf16 partials (O/s) + (m, s) into the dead Wqt/Wkt/Wvt region;
// merge_kernel combines exactly (log-sum-exp weights) before oproj. No new sync primitives.
static __device__ const unsigned char kOrder[43] = {
  84, 83, 82, 81, 80,           // solo qt=20..16  (len 21..17)
  62, 63, 60,                   // 31h0, 31h1, 30h0 (16)
  79,                           // solo15 (16)
  61, 58, 59, 56,               // 30h1, 29h0, 29h1, 28h0 (15)
  78,                           // solo14 (15)
  57, 54, 55, 52,               // 28h1, 27h0, 27h1, 26h0 (14)
  77,                           // solo13 (14)
  53, 50, 51, 48,               // 26h1, 25h0, 25h1, 24h0 (13)
  76,                           // solo12 (13)
  49, 46, 47, 44,               // 24h1, 23h0, 23h1, 22h0 (12)
  75,                           // solo11 (12)
  45, 42, 43,                   // 22h1, 21h0, 21h1 (11)
  74,                           // solo10 (11)
  73, 72, 71, 70, 69, 68, 67, 66, 65, 64  // solo qt=9..0
};

__global__ __launch_bounds__(512, 4) void attn_kernel(const u16* __restrict__ Qb,
                                                      const u16* __restrict__ Kb,
                                                      const u16* __restrict__ Vb,
                                                      u16* __restrict__ Ab,
                                                      u16* __restrict__ Opart,
                                                      float* __restrict__ msBuf) {
  const int e = kOrder[blockIdx.x >> 4];
  const int combo = blockIdx.x & 15;
  const int kh = combo & 7, b = combo >> 3;
  int qt, kvlo, kvhi, chk;
  if (e >= 64) { qt = e - 64; kvlo = 0; kvhi = qt + 1; chk = -1; }
  else {
    qt = e >> 1;
    const int half = e & 1;
    const int mid = (qt + 2) >> 1;
    kvlo = half ? mid : 0;
    kvhi = half ? qt + 1 : mid;
    chk = (combo * 11 + (qt - 21)) * 2 + half;
  }

  const int tid = threadIdx.x;
  const int lane = tid & 63, wv = tid >> 6;
  const int hh = wv & 3, qh = wv >> 2;      // head-in-group, q-half
  const int h = kh * 4 + hh;
  const int l31 = lane & 31, hi = lane >> 5;
  const int swz = (l31 & 7) << 3;

  __shared__ __align__(16) u16 Ks[2][64 * 64];   // K[kv][d ^ ((kv&7)<<3)] (gl_lds, rule #21)
  __shared__ __align__(16) u16 Vt[2][64 * 68];   // V^T[d][kv], stride 68 (2-way banks)

  const int skv = tid >> 3;
  const int sc8 = tid & 7;
  const int sd0 = sc8 * 8;

  const u16* Kbase = Kb + (size_t)(b * 2048) * 512 + kh * 64;
  const u16* Vbase = Vb + (size_t)(b * 2048) * 512 + kh * 64;

  const int q0 = qt * 64;

  // Q B-frags: col = q = l31, k = d = c*16 + hi*8 + j
  bf16x8 qf[4];
  {
    const u16* qp = Qb + (size_t)(b * 2048 + q0 + qh * 32 + l31) * 2048 + h * 64 + hi * 8;
#pragma unroll
    for (int c = 0; c < 4; c++) qf[c] = *(const bf16x8*)(qp + c * 16);
  }
  f32x16 ot[2] = {};
  float mrow = -30000.0f, srow = 0.f;

  int cur = 0;
  {  // prologue: stage tile kvlo into buf 0
    gl_lds16(&Ks[0][wv << 9], Kbase + (((size_t)(kvlo * 64 + skv)) << 9) + ((sc8 ^ (skv & 7)) << 3));
    u16x8 vr = *(const u16x8*)(Vbase + (((size_t)(kvlo * 64 + skv)) << 9) + sd0);
#pragma unroll
    for (int j8 = 0; j8 < 8; j8++) {
      const int jj = (j8 + sc8) & 7;
      const int d = sd0 + jj;
      Vt[0][d * 68 + skv] = vr[jj];
    }
  }
  for (int it = kvlo; it < kvhi; ++it) {
    __syncthreads();
    const bool pre = (it + 1 < kvhi);
    u16x8 vnx;
    if (pre) {
      const size_t roff = (size_t)((it + 1) * 64 + skv) << 9;
      gl_lds16(&Ks[cur ^ 1][wv << 9], Kbase + roff + ((sc8 ^ (skv & 7)) << 3));
      vnx = *(const u16x8*)(Vbase + roff + sd0);
    }
    const u16* Kc = Ks[cur];
    const u16* Vc = Vt[cur];

    // S = K Q
    f32x16 sc2[2] = {};
#pragma unroll
    for (int c = 0; c < 4; c++) {
      const int dblk = (c * 16 + hi * 8) ^ swz;
#pragma unroll
      for (int kvh = 0; kvh < 2; kvh++) {
        bf16x8 kf = *(const bf16x8*)&Kc[(kvh * 32 + l31) * 64 + dblk];
        sc2[kvh] = MFMA32(kf, qf[c], sc2[kvh]);
      }
    }
    if (it == qt) {  // causal mask on diagonal tile
      const int q = qh * 32 + l31;
#pragma unroll
      for (int kvh = 0; kvh < 2; kvh++)
#pragma unroll
        for (int r = 0; r < 16; r++) {
          const int kv = kvh * 32 + (r & 3) + 8 * (r >> 2) + 4 * hi;
          if (kv > q) sc2[kvh][r] = -30000.0f;
        }
    }
    // row max: in-register + partner exchange
    float tm = fmaxf(sc2[0][0], sc2[0][1]);
#pragma unroll
    for (int kvh = 0; kvh < 2; kvh++)
#pragma unroll
      for (int r = (kvh ? 0 : 2); r < 16; r++) tm = fmaxf(tm, sc2[kvh][r]);
    tm = fmaxf(tm, __shfl_xor(tm, 32));
    // defer-max (T13)
    if (__any(tm > mrow + 8.0f)) {
      const float mnew = fmaxf(mrow, tm);
      const float scl = __builtin_amdgcn_exp2f(mrow - mnew);
      mrow = mnew;
      srow *= scl;
#pragma unroll
      for (int dh = 0; dh < 2; dh++)
#pragma unroll
        for (int r = 0; r < 16; r++) ot[dh][r] *= scl;
    }
    // P = exp2(S - m); PV per kvh-half
    float ps = 0.f;
#pragma unroll
    for (int kvh = 0; kvh < 2; kvh++) {
      unsigned pk[8];
#pragma unroll
      for (int j8 = 0; j8 < 8; j8++) {
        const float p0 = __builtin_amdgcn_exp2f(sc2[kvh][2 * j8] - mrow);
        const float p1 = __builtin_amdgcn_exp2f(sc2[kvh][2 * j8 + 1] - mrow);
        ps += p0 + p1;
        pk[j8] = pack2(p0, p1);
      }
#pragma unroll
      for (int tt = 0; tt < 2; tt++) {
        const int t = kvh * 2 + tt;
        const unsigned a0 = pk[4 * tt + 0], a1 = pk[4 * tt + 1];
        const unsigned b0 = pk[4 * tt + 2], b1 = pk[4 * tt + 3];
        const unsigned s0 = hi ? a0 : b0, s1 = hi ? a1 : b1;
        const unsigned r0 = (unsigned)__shfl_xor((int)s0, 32);
        const unsigned r1 = (unsigned)__shfl_xor((int)s1, 32);
        u32x4 pw;
        pw[0] = hi ? r0 : a0;
        pw[1] = hi ? r1 : a1;
        pw[2] = hi ? b0 : r0;
        pw[3] = hi ? b1 : r1;
        const bf16x8 pf = __builtin_bit_cast(bf16x8, pw);
#pragma unroll
        for (int dh = 0; dh < 2; dh++) {
          bf16x8 vf = ld2x64(&Vc[(dh * 32 + l31) * 68 + t * 16 + hi * 8]);
          ot[dh] = MFMA32(vf, pf, ot[dh]);
        }
      }
    }
    ps += __shfl_xor(ps, 32);
    srow += ps;
    if (pre) {
#pragma unroll
      for (int j8 = 0; j8 < 8; j8++) {
        const int jj = (j8 + sc8) & 7;
        const int d = sd0 + jj;
        Vt[cur ^ 1][d * 68 + skv] = vnx[jj];
      }
    }
    cur ^= 1;
  }
  // partial chunks: store (m, s) per q-row (both partner lanes hold identical values)
  if (chk >= 0 && hi == 0) {
    const int msb = ((chk * 4 + hh) * 64 + qh * 32 + l31) * 2;
    msBuf[msb] = mrow;
    msBuf[msb + 1] = srow;
  }
  // epilogue: transpose O^T -> O through LDS (K/V buffers are dead), coalesced store
  __syncthreads();
  u16* Sx = (wv < 4) ? &Ks[0][0] + wv * 2048 : &Vt[0][0] + (wv - 4) * 2048;
  const float inv = 1.0f / srow;
#pragma unroll
  for (int dh = 0; dh < 2; dh++)
#pragma unroll
    for (int jr = 0; jr < 8; jr++) {
      const unsigned w = pack2(ot[dh][2 * jr] * inv, ot[dh][2 * jr + 1] * inv);
      const int d = dh * 32 + 8 * (jr >> 1) + (jr & 1) * 2 + 4 * hi;
      *(unsigned*)&Sx[l31 * 64 + (d ^ swz)] = w;
    }
  __syncthreads();
#pragma unroll
  for (int rep = 0; rep < 4; rep++) {
    const int u = rep * 64 + lane;
    const int qr = u >> 3, cc = u & 7;
    u16x8 val = *(const u16x8*)&Sx[qr * 64 + ((cc * 8) ^ ((qr & 7) << 3))];
    if (chk < 0)
      *(u16x8*)&Ab[(size_t)(b * 2048 + q0 + qh * 32 + qr) * 2048 + h * 64 + cc * 8] = val;
    else
      *(u16x8*)&Opart[(size_t)((chk * 4 + hh) * 64 + qh * 32 + qr) * 64 + cc * 8] = val;
  }
}

// ---------------- merge: combine the two KV-half partials of each split tile ----------------
// O = (O1*w1 + O2*w2)/(w1+w2), w_i = s_i * 2^(m_i - max(m1,m2))  — exact log-sum-exp merge.
__global__ __launch_bounds__(256) void merge_kernel(const u16* __restrict__ Opart,
                                                    const float* __restrict__ msBuf,
                                                    u16* __restrict__ Ab) {
  const int sp = blockIdx.x, h = blockIdx.y;          // sp 0..175, h 0..3
  const int combo = sp / 11, qt = 21 + sp % 11;
  const int kh = combo & 7, b = combo >> 3;
  const int c0 = (sp * 2) * 4 + h, c1 = (sp * 2 + 1) * 4 + h;
#pragma unroll
  for (int u = threadIdx.x; u < 512; u += 256) {
    const int q = u >> 3, dc = u & 7;
    const float m1 = msBuf[(c0 * 64 + q) * 2], s1 = msBuf[(c0 * 64 + q) * 2 + 1];
    const float m2 = msBuf[(c1 * 64 + q) * 2], s2 = msBuf[(c1 * 64 + q) * 2 + 1];
    const float m = fmaxf(m1, m2);
    const float w1 = s1 * __builtin_amdgcn_exp2f(m1 - m);
    const float w2 = s2 * __builtin_amdgcn_exp2f(m2 - m);
    const float inv = 1.0f / (w1 + w2);
    u16x8 o1 = *(const u16x8*)&Opart[(size_t)(c0 * 64 + q) * 64 + dc * 8];
    u16x8 o2 = *(const u16x8*)&Opart[(size_t)(c1 * 64 + q) * 64 + dc * 8];
    u16x8 out;
#pragma unroll
    for (int jj = 0; jj < 8; jj++)
      out[jj] = f2b((b2f(o1[jj]) * w1 + b2f(o2[jj]) * w2) * inv);
    *(u16x8*)&Ab[(size_t)(b * 2048 + qt * 64 + q) * 2048 + (kh * 4 + h) * 64 + dc * 8] = out;
  }
}

extern "C" void kernel_launch(void* const* d_in, const int* in_sizes, int n_in,
                              void* d_out, int out_size, void* d_ws, size_t ws_size,
                              hipStream_t stream) {
  const float* x  = (const float*)d_in[0];
  const float* Wq = (const float*)d_in[1];
  const float* bq = (const float*)d_in[2];
  const float* Wk = (const float*)d_in[3];
  const float* bk = (const float*)d_in[4];
  const float* Wv = (const float*)d_in[5];
  const float* bv = (const float*)d_in[6];
  const float* Wo = (const float*)d_in[7];
  const float* bo = (const float*)d_in[8];

  char* ws = (char*)d_ws;
  u16* xb  = (u16*)(ws + 0);          // 4096*2048 bf16 = 16 MiB
  u16* Ab  = (u16*)(ws + 0);          // aliases xb (xb dead after QKV gemm)
  u16* Qb  = (u16*)(ws + 16777216);   // 4096*2048
  u16* Kb  = (u16*)(ws + 33554432);   // 4096*512
  u16* Vb  = (u16*)(ws + 37748736);   // 4096*512
  u16* Wqt = (u16*)(ws + 41943040);   // 2048*2048 (dead after qkv -> reused as Opart)
  u16* Wkt = (u16*)(ws + 50331648);   // 512*2048  (dead after qkv)
  u16* Wvt = (u16*)(ws + 52428800);   // 512*2048  (dead after qkv)
  u16* Wot = (u16*)(ws + 54525952);   // 2048*2048 (live until oproj)
  // split-KV partials overlay the dead Wqt..Wvt region (12.58 MB):
  u16*   Opart = (u16*)(ws + 41943040);            // 352 chunks * 32 KiB = 11,534,336 B
  float* msBuf = (float*)(ws + 41943040 + 11534336); // 352*4*64 float2 = 720,896 B (< region end)

  cvt_fused_kernel<<<dim3(8192 + 160 * 64), 256, 0, stream>>>(
      x, xb, Wq, Wk, Wv, Wo, Wqt, Wkt, Wvt, Wot);

  qkv_gemm_kernel<<<dim3(24, 32), 512, 0, stream>>>(xb, Wqt, Wkt, Wvt, bq, bk, bv, Qb, Kb, Vb);
  attn_kernel<<<dim3(16 * 43), 512, 0, stream>>>(Qb, Kb, Vb, Ab, Opart, msBuf);
  merge_kernel<<<dim3(176, 4), 256, 0, stream>>>(Opart, msBuf, Ab);
  oproj_kernel<<<dim3(16, 32), 512, 0, stream>>>(Ab, Wot, bo, (float*)d_out);
}